// Round 19
// baseline (75.588 us; speedup 1.0000x reference)
//
#include <hip/hip_runtime.h>
#include <hip/hip_fp16.h>

#define OUTF 11008
#define INF  4096
#define NTILES 688
#define REPL 6

typedef unsigned int uint;
typedef __attribute__((ext_vector_type(8))) _Float16 f16x8;  // MFMA A/B (4 VGPR)
typedef __attribute__((ext_vector_type(4))) float f32x4;     // MFMA C/D

typedef __attribute__((address_space(1))) void gvoid_t;
typedef __attribute__((address_space(3))) void svoid_t;

union UA { uint4 u4; uint u[4]; f16x8 v; };
union UH { uint u; __half2 h; };
union USH { unsigned short s; __half h; };

#define WAITV(n) asm volatile("s_waitcnt vmcnt(" #n ")" ::: "memory")
#define FENCE()  asm volatile("" ::: "memory")
#define BARRIER() { FENCE(); __builtin_amdgcn_s_barrier(); FENCE(); }

// R17 structure, 6x tile-replicated for profiler visibility. Replicas
// (bid >= 688) run the identical pipeline on tile bid%688, skip the store.
__global__ __launch_bounds__(256, 3) void lin2bit_kernel(
    const float* __restrict__ x, const int* __restrict__ wq,
    const float* __restrict__ wn, const float* __restrict__ bias,
    float* __restrict__ out)
{
  __shared__ __align__(16) char lds[51200];
  char* LUT = lds;
  char* NL  = lds + 2048;
  char* X0  = lds + 10240;
  char* X1  = lds + 26624;
  char* W0  = lds + 43008;
  char* W1  = lds + 47104;

  const int tid = threadIdx.x;
  const int wv  = tid >> 6;
  const int l   = tid & 63;
  const int col = l & 15;
  const int q   = l >> 4;
  const int bid = (int)blockIdx.x;
  int tile = bid;
  if (tile >= 2752) tile -= 2752;
  if (tile >= 1376) tile -= 1376;
  if (tile >= 688)  tile -= 688;
  const int o0  = tile << 4;

  const char* xb  = (const char*)x;
  const char* wqb = (const char*)wq;
  const char* wnb = (const char*)wn;

  // ---- norms DMA once: 8 KB, 8 instr (2/wave); 16B-granule swizzle key r&7
  {
#pragma unroll
    for (int ii = 0; ii < 2; ++ii) {
      const int i = wv * 2 + ii;
      const int r = 2 * i + (l >> 5);
      const char* src = wnb + (size_t)(o0 + r) * 512 + (((l & 31) ^ (r & 7)) << 4);
      __builtin_amdgcn_global_load_lds((gvoid_t*)src,
                                       (svoid_t*)(NL + i * 1024 + l * 16), 16, 0, 0);
    }
  }
  FENCE();

#define STAGE_X(c, buf) { \
    _Pragma("unroll") \
    for (int ii = 0; ii < 4; ++ii) { \
      const int i = wv * 4 + ii; \
      const char* src = xb + (size_t)i * 16384 + (size_t)(c) * 1024 \
                        + ((((l >> 1) ^ (i & 7)) << 5) | ((l & 1) << 4)); \
      __builtin_amdgcn_global_load_lds((gvoid_t*)src, \
                                       (svoid_t*)((buf) + i * 1024 + l * 16), 16, 0, 0); \
    } }

#define STAGE_W(c, buf) { \
    const int r = wv * 4 + (l >> 4); \
    const char* src = wqb + (size_t)(o0 + r) * 4096 + (size_t)(c) * 256 \
                      + (((l & 15) ^ (r & 7)) << 4); \
    __builtin_amdgcn_global_load_lds((gvoid_t*)src, \
                                     (svoid_t*)((buf) + wv * 1024 + l * 16), 16, 0, 0); }

  STAGE_X(0, X0); STAGE_W(0, W0); FENCE();
  STAGE_X(1, X1); STAGE_W(1, W1); FENCE();

  // ---- LUT build on VALU while DMAs fly
  {
    USH h0, h1, h2, h3;
    h0.h = __float2half(-1.0f);  h1.h = __float2half(-0.333f);
    h2.h = __float2half(0.333f); h3.h = __float2half(1.0f);
    const uint hv[4] = {h0.s, h1.s, h2.s, h3.s};
#pragma unroll
    for (int e = 0; e < 4; ++e) {
      const int idx = e * 64 + l;
      const uint lo = hv[idx & 3]        | (hv[(idx >> 2) & 3] << 16);
      const uint hi = hv[(idx >> 4) & 3] | (hv[(idx >> 6) & 3] << 16);
      *(uint2*)(LUT + idx * 8) = make_uint2(lo, hi);
    }
  }

  f32x4 acc = {0.f, 0.f, 0.f, 0.f};
  const int c7 = col & 7;

#define COMPUTE(c, xs, ws) { \
    const int naddr = col * 512 + ((((c) * 2 + (wv >> 1)) ^ c7) << 4) + (wv & 1) * 8; \
    const float2 nn = *(const float2*)(NL + naddr); \
    _Pragma("unroll") \
    for (int jj = 0; jj < 2; ++jj) { \
      const int g = wv * 2 + jj; \
      const float nv = jj ? nn.y : nn.x; \
      UH nvh; nvh.h = __floats2half2_rn(nv, nv); \
      const uint2 p = *(const uint2*)((ws) + col * 256 \
                        + (((g * 2 + (q >> 1)) ^ c7) << 4) + (q & 1) * 8); \
      const int xaddr = col * 1024 + (((g * 4 + q) ^ c7) << 5); \
      const float4 xa = *(const float4*)((xs) + xaddr); \
      const float4 xc = *(const float4*)((xs) + xaddr + 16); \
      UH k0, k1, k2, k3; \
      k0.h = __floats2half2_rn(xa.x, xa.y); k1.h = __floats2half2_rn(xa.z, xa.w); \
      k2.h = __floats2half2_rn(xc.x, xc.y); k3.h = __floats2half2_rn(xc.z, xc.w); \
      UA A; A.u[0] = k0.u; A.u[1] = k1.u; A.u[2] = k2.u; A.u[3] = k3.u; \
      const uint2 e0 = *(const uint2*)(LUT + ((size_t)(uint)p.x << 3)); \
      const uint2 e1 = *(const uint2*)(LUT + ((size_t)(uint)p.y << 3)); \
      UH a0, a1, a2, a3, b0, b1, b2, b3; \
      a0.u = e0.x; a1.u = e0.y; a2.u = e1.x; a3.u = e1.y; \
      b0.h = __hmul2(a0.h, nvh.h); b1.h = __hmul2(a1.h, nvh.h); \
      b2.h = __hmul2(a2.h, nvh.h); b3.h = __hmul2(a3.h, nvh.h); \
      UA B; B.u[0] = b0.u; B.u[1] = b1.u; B.u[2] = b2.u; B.u[3] = b3.u; \
      acc = __builtin_amdgcn_mfma_f32_16x16x32_f16(A.v, B.v, acc, 0, 0, 0); \
    } }

#define ITER_FULL(c, XS, WS) \
  WAITV(5); BARRIER(); \
  COMPUTE(c, XS, WS) \
  BARRIER(); \
  STAGE_X((c) + 2, XS); STAGE_W((c) + 2, WS); FENCE();

  ITER_FULL(0,  X0, W0)  ITER_FULL(1,  X1, W1)
  ITER_FULL(2,  X0, W0)  ITER_FULL(3,  X1, W1)
  ITER_FULL(4,  X0, W0)  ITER_FULL(5,  X1, W1)
  ITER_FULL(6,  X0, W0)  ITER_FULL(7,  X1, W1)
  ITER_FULL(8,  X0, W0)  ITER_FULL(9,  X1, W1)
  ITER_FULL(10, X0, W0)  ITER_FULL(11, X1, W1)
  ITER_FULL(12, X0, W0)  ITER_FULL(13, X1, W1)
  WAITV(5); BARRIER(); COMPUTE(14, X0, W0)
  WAITV(0); BARRIER(); COMPUTE(15, X1, W1)
#undef ITER_FULL
#undef COMPUTE
#undef STAGE_X
#undef STAGE_W

  // ---- cross-wave K reduction + bias + store (replicas skip only the store)
  __syncthreads();
  float* red = (float*)lds;
  red[wv * 256 +   0 + l] = acc[0];
  red[wv * 256 +  64 + l] = acc[1];
  red[wv * 256 + 128 + l] = acc[2];
  red[wv * 256 + 192 + l] = acc[3];
  __syncthreads();
  const int t = tid;
  const float s = red[t] + red[256 + t] + red[512 + t] + red[768 + t];
  const int m  = ((t & 63) >> 4) * 4 + (t >> 6);
  const int oc = t & 15;
  if (bid < NTILES)
    out[(size_t)m * OUTF + o0 + oc] = s + bias[o0 + oc];
}

extern "C" void kernel_launch(void* const* d_in, const int* in_sizes, int n_in,
                              void* d_out, int out_size, void* d_ws, size_t ws_size,
                              hipStream_t stream) {
  (void)in_sizes; (void)n_in; (void)out_size; (void)d_ws; (void)ws_size;
  const float* x    = (const float*)d_in[0];
  const int*   wq   = (const int*)d_in[1];
  const float* wn   = (const float*)d_in[2];
  const float* bias = (const float*)d_in[3];
  float*       out  = (float*)d_out;
  lin2bit_kernel<<<dim3(REPL * NTILES), dim3(256), 0, stream>>>(x, wq, wn, bias, out);
}

// Round 22
// 19.664 us; speedup vs baseline: 3.8439x; 3.8439x over previous
//
#include <hip/hip_runtime.h>
#include <hip/hip_fp16.h>

#define OUTF 11008
#define INF  4096
#define NTILES 688

typedef unsigned int uint;
typedef __attribute__((ext_vector_type(8))) _Float16 f16x8;  // MFMA A/B (4 VGPR)
typedef __attribute__((ext_vector_type(4))) float f32x4;     // MFMA C/D

typedef __attribute__((address_space(1))) void gvoid_t;
typedef __attribute__((address_space(3))) void svoid_t;

union UA { uint4 u4; uint u[4]; f16x8 v; };
union UH { uint u; __half2 h; };
union USH { unsigned short s; __half h; };

#define WAITV(n) asm volatile("s_waitcnt vmcnt(" #n ")" ::: "memory")
#define WAITL()  asm volatile("s_waitcnt lgkmcnt(0)" ::: "memory")
#define SBAR()   __builtin_amdgcn_sched_barrier(0)
#define FENCE()  asm volatile("" ::: "memory")
#define BARRIER() { FENCE(); __builtin_amdgcn_s_barrier(); FENCE(); }

// Single kernel. Block = 256 thr = 4 waves, one 16-row o-tile, 16 chunks of
// 256k. X reg-staged f32->f16 into LDS (floor-achieving 16B-granule XOR
// swizzle); W via global_load_lds DMA; LUT dequant.
// R21 fix: sched_barrier(0) after each WAITV (rule #18 — cvts reading asm-load
// destinations were hoisted above the s_waitcnt).
__global__ __launch_bounds__(256, 4) void lin2bit_kernel(
    const float* __restrict__ x, const int* __restrict__ wq,
    const float* __restrict__ wn, const float* __restrict__ bias,
    float* __restrict__ out)
{
  // LUT 2K | NL 8K | X0 8K | X1 8K | W0 4K | W1 4K = 34K -> 4 blocks/CU
  __shared__ __align__(16) char lds[34816];
  char* LUT = lds;
  char* NL  = lds + 2048;
  char* X0  = lds + 10240;
  char* X1  = lds + 18432;
  char* W0  = lds + 26624;
  char* W1  = lds + 30720;

  const int tid = threadIdx.x;
  const int wv  = tid >> 6;
  const int l   = tid & 63;
  const int col = l & 15;            // A-row (m) / B-col (o)
  const int q   = l >> 4;            // lane covers k = 8q..8q+7 of each group
  const int o0  = (int)blockIdx.x << 4;

  const char* xb  = (const char*)x;
  const char* wqb = (const char*)wq;
  const char* wnb = (const char*)wn;

  // ---- norms DMA once: 8 KB, 2 instr/wave; 16B-granule swizzle key r&7
  {
#pragma unroll
    for (int ii = 0; ii < 2; ++ii) {
      const int i = wv * 2 + ii;
      const int r = 2 * i + (l >> 5);
      const char* src = wnb + (size_t)(o0 + r) * 512 + (((l & 31) ^ (r & 7)) << 4);
      __builtin_amdgcn_global_load_lds((gvoid_t*)src,
                                       (svoid_t*)(NL + i * 1024 + l * 16), 16, 0, 0);
    }
  }
  FENCE();

  // X loads: wave's 4 m-rows, 1 KB each, coalesced; asm volatile (un-sinkable)
#define XLOAD(c, xr) { \
    _Pragma("unroll") \
    for (int rr = 0; rr < 4; ++rr) { \
      const int r = wv * 4 + rr; \
      const float* srcp = (const float*)(xb + (size_t)r * 16384 + (size_t)(c) * 1024) + l * 4; \
      asm volatile("global_load_dwordx4 %0, %1, off" \
                   : "=&v"((xr)[rr]) : "v"(srcp) : "memory"); \
    } }

  // X write: cvt f32->f16, swizzled ds_write_b64 (granule (l>>1)^(r&7), half l&1)
#define XWRITE(buf, xr) { \
    _Pragma("unroll") \
    for (int rr = 0; rr < 4; ++rr) { \
      const int r = wv * 4 + rr; \
      UH h0, h1; \
      h0.h = __floats2half2_rn((xr)[rr].x, (xr)[rr].y); \
      h1.h = __floats2half2_rn((xr)[rr].z, (xr)[rr].w); \
      *(uint2*)((buf) + r * 512 + (((l >> 1) ^ (r & 7)) << 4) + (l & 1) * 8) = \
          make_uint2(h0.u, h1.u); \
    } }

  // W chunk: 16 rows x 256B, 1 DMA/wave, 16B-granule source-side swizzle
#define WSTAGE(c, buf) { \
    const int r = wv * 4 + (l >> 4); \
    const char* src = wqb + (size_t)(o0 + r) * 4096 + (size_t)(c) * 256 \
                      + (((l & 15) ^ (r & 7)) << 4); \
    __builtin_amdgcn_global_load_lds((gvoid_t*)src, \
                                     (svoid_t*)((buf) + wv * 1024 + l * 16), 16, 0, 0); }

  float4 xrA[4], xrB[4];
  XLOAD(0, xrA);   FENCE();
  WSTAGE(0, W0);   FENCE();
  XLOAD(1, xrB);   FENCE();
  WSTAGE(1, W1);   FENCE();
  // FIFO: N(2) XL0(4) W0(1) XL1(4) W1(1) = 12

  // ---- LUT build on VALU while loads fly
  {
    USH h0, h1, h2, h3;
    h0.h = __float2half(-1.0f);  h1.h = __float2half(-0.333f);
    h2.h = __float2half(0.333f); h3.h = __float2half(1.0f);
    const uint hv[4] = {h0.s, h1.s, h2.s, h3.s};
#pragma unroll
    for (int e = 0; e < 4; ++e) {
      const int idx = e * 64 + l;
      const uint lo = hv[idx & 3]        | (hv[(idx >> 2) & 3] << 16);
      const uint hi = hv[(idx >> 4) & 3] | (hv[(idx >> 6) & 3] << 16);
      *(uint2*)(LUT + idx * 8) = make_uint2(lo, hi);
    }
  }

  WAITV(5); SBAR();         // retire N+XL0+W0; keep XL1(4)+W1(1)
  XWRITE(X0, xrA);
  WAITL(); BARRIER();       // X0 written block-wide; W0 retired per-wave

  f32x4 acc = {0.f, 0.f, 0.f, 0.f};
  const int c7 = col & 7;

#define COMPUTE(c, xs, ws) { \
    const float2 nn = *(const float2*)(NL + col * 512 \
                        + ((((c) * 2 + (wv >> 1)) ^ c7) << 4) + (wv & 1) * 8); \
    _Pragma("unroll") \
    for (int jj = 0; jj < 2; ++jj) { \
      const int g = wv * 2 + jj; \
      const float nv = jj ? nn.y : nn.x; \
      UH nvh; nvh.h = __floats2half2_rn(nv, nv); \
      const uint2 p = *(const uint2*)((ws) + col * 256 \
                        + (((g * 2 + (q >> 1)) ^ c7) << 4) + (q & 1) * 8); \
      UA A; A.u4 = *(const uint4*)((xs) + col * 512 + (((g * 4 + q) ^ c7) << 4)); \
      const uint2 e0 = *(const uint2*)(LUT + ((size_t)(uint)p.x << 3)); \
      const uint2 e1 = *(const uint2*)(LUT + ((size_t)(uint)p.y << 3)); \
      UH a0, a1, a2, a3, b0, b1, b2, b3; \
      a0.u = e0.x; a1.u = e0.y; a2.u = e1.x; a3.u = e1.y; \
      b0.h = __hmul2(a0.h, nvh.h); b1.h = __hmul2(a1.h, nvh.h); \
      b2.h = __hmul2(a2.h, nvh.h); b3.h = __hmul2(a3.h, nvh.h); \
      UA B; B.u[0] = b0.u; B.u[1] = b1.u; B.u[2] = b2.u; B.u[3] = b3.u; \
      acc = __builtin_amdgcn_mfma_f32_16x16x32_f16(A.v, B.v, acc, 0, 0, 0); \
    } }

  // iter c: compute c | load c+2 | barrier | W-stage c+2 | wait | write X(c+1)
#define ITER_FULL(c, XC, WC, XN, XRC, XRN) \
  COMPUTE(c, XC, WC) \
  XLOAD((c) + 2, XRC);  FENCE(); \
  BARRIER(); \
  WSTAGE((c) + 2, WC);  FENCE(); \
  WAITV(5); SBAR(); \
  XWRITE(XN, XRN); \
  WAITL(); BARRIER();

  ITER_FULL(0,  X0, W0, X1, xrA, xrB)
  ITER_FULL(1,  X1, W1, X0, xrB, xrA)
  ITER_FULL(2,  X0, W0, X1, xrA, xrB)
  ITER_FULL(3,  X1, W1, X0, xrB, xrA)
  ITER_FULL(4,  X0, W0, X1, xrA, xrB)
  ITER_FULL(5,  X1, W1, X0, xrB, xrA)
  ITER_FULL(6,  X0, W0, X1, xrA, xrB)
  ITER_FULL(7,  X1, W1, X0, xrB, xrA)
  ITER_FULL(8,  X0, W0, X1, xrA, xrB)
  ITER_FULL(9,  X1, W1, X0, xrB, xrA)
  ITER_FULL(10, X0, W0, X1, xrA, xrB)
  ITER_FULL(11, X1, W1, X0, xrB, xrA)
  ITER_FULL(12, X0, W0, X1, xrA, xrB)
  ITER_FULL(13, X1, W1, X0, xrB, xrA)
  // iter 14: no further staging
  COMPUTE(14, X0, W0)
  BARRIER();
  WAITV(0); SBAR();
  XWRITE(X1, xrB);
  WAITL(); BARRIER();
  COMPUTE(15, X1, W1)
#undef ITER_FULL
#undef COMPUTE
#undef XLOAD
#undef XWRITE
#undef WSTAGE

  // ---- cross-wave K reduction (overlay on LUT+NL) + bias + store
  __syncthreads();
  float* red = (float*)lds;
  red[wv * 256 +   0 + l] = acc[0];
  red[wv * 256 +  64 + l] = acc[1];
  red[wv * 256 + 128 + l] = acc[2];
  red[wv * 256 + 192 + l] = acc[3];
  __syncthreads();
  const int t = tid;
  const float s = red[t] + red[256 + t] + red[512 + t] + red[768 + t];
  const int m  = ((t & 63) >> 4) * 4 + (t >> 6);   // D row = q*4 + reg
  const int oc = t & 15;                            // D col
  out[(size_t)m * OUTF + o0 + oc] = s + bias[o0 + oc];
}

extern "C" void kernel_launch(void* const* d_in, const int* in_sizes, int n_in,
                              void* d_out, int out_size, void* d_ws, size_t ws_size,
                              hipStream_t stream) {
  (void)in_sizes; (void)n_in; (void)out_size; (void)d_ws; (void)ws_size;
  const float* x    = (const float*)d_in[0];
  const int*   wq   = (const int*)d_in[1];
  const float* wn   = (const float*)d_in[2];
  const float* bias = (const float*)d_in[3];
  float*       out  = (float*)d_out;
  lin2bit_kernel<<<dim3(NTILES), dim3(256), 0, stream>>>(x, wq, wn, bias, out);
}